// Round 14
// baseline (1069.114 us; speedup 1.0000x reference)
//
#include <hip/hip_runtime.h>
#include <hip/hip_cooperative_groups.h>

namespace cg = cooperative_groups;

#define NNODES 50000
#define NEDGES 800000
#define F_IN   128
#define HID    256
#define NOUT   40
#define NBLK_SCAN ((NNODES + 255) / 256)  // 196
#define NBLK_CAST 6250                     // 50000*128/4/256
#define NBLK_PREP 432                      // 128 (W1) + 256 (W2) + 48 (Wc)
#define EDGE_CHUNK 3125                    // 800000 / 256
#define NODES_PER_G 6250                   // 50000 / 8
#define CSR_BLOCKS 2048                    // 8 blocks/CU x 256 CU

// workspace layout (bytes)
#define OFF_COUNT    0         // 50000 ints
#define OFF_CURSOR   200064    // 50000 ints   (zero range = [0, 400128))
#define OFF_ROWSTART 400128
#define OFF_DINV     600320
#define OFF_CSR      800384    // 3.2 MB
#define OFF_BSUM     4000512
#define OFF_BOFF     4001536
#define OFF_W1T      4002560   // 256x128 fp16
#define OFF_W2T      4068096   // 256x256 fp16
#define OFF_WCT      4199168   // 48x256 fp16
#define OFF_XH       4264704   // 50000x128 fp16
#define OFF_AGGX     17064704  // 50000x128 fp16
#define OFF_H1       29864704  // 50000x256 fp16
#define OFF_AGGH     55464704  // 50000x256 fp16

typedef __attribute__((ext_vector_type(8))) _Float16 f16x8;
typedef __attribute__((ext_vector_type(4))) float f32x4;
typedef __attribute__((ext_vector_type(4))) unsigned short u16x4;
typedef __attribute__((ext_vector_type(8))) unsigned short u16x8;

__device__ __forceinline__ unsigned short f2h(float f) {
  return __builtin_bit_cast(unsigned short, (_Float16)f);
}
__device__ __forceinline__ float h2f(unsigned short u) {
  return (float)__builtin_bit_cast(_Float16, u);
}

// ---------------- cooperative CSR build ----------------
// One launch: zero | cast | prep -> sync -> degree -> sync -> scan ->
// sync -> blocksum scan -> sync -> scatter. XCD-local phases use
// blockIdx&7 (speed heuristic only).

__global__ __launch_bounds__(256, 8) void k_csr(const float* __restrict__ X,
                                                const int* __restrict__ srcE,
                                                const int* __restrict__ dstE,
                                                const float* __restrict__ W1,
                                                const float* __restrict__ W2,
                                                const float* __restrict__ Wc,
                                                char* __restrict__ ws) {
  cg::grid_group grid = cg::this_grid();
  int b = blockIdx.x, t = threadIdx.x;
  int* count    = (int*)(ws + OFF_COUNT);
  int* cursor   = (int*)(ws + OFF_CURSOR);
  int* rowstart = (int*)(ws + OFF_ROWSTART);
  float* dinv   = (float*)(ws + OFF_DINV);
  int* csr      = (int*)(ws + OFF_CSR);
  int* bsum     = (int*)(ws + OFF_BSUM);
  int* boff     = (int*)(ws + OFF_BOFF);
  unsigned short* T1 = (unsigned short*)(ws + OFF_W1T);
  unsigned short* T2 = (unsigned short*)(ws + OFF_W2T);
  unsigned short* Tc = (unsigned short*)(ws + OFF_WCT);
  unsigned short* Xh = (unsigned short*)(ws + OFF_XH);
  (void)cursor;

  // ---- phase 0: zero count+cursor | x->fp16 cast | weight transpose ----
  {
    int gi = b * 256 + t;
    if (gi < 100032) ((int*)ws)[gi] = 0;  // count + cursor (+ padding)
    for (int c = b; c < NBLK_CAST; c += CSR_BLOCKS) {
      int i = c * 256 + t;
      float4 v = *reinterpret_cast<const float4*>(X + (size_t)i * 4);
      ushort4 o;
      o.x = f2h(v.x); o.y = f2h(v.y); o.z = f2h(v.z); o.w = f2h(v.w);
      *reinterpret_cast<ushort4*>(Xh + (size_t)i * 4) = o;
    }
    for (int c = b; c < NBLK_PREP; c += CSR_BLOCKS) {
      if (c < 128) {                       // W1 [128][256] -> T1 [256][128]
        int idx = c * 256 + t;
        int n = idx >> 7, k = idx & 127;
        T1[idx] = f2h(W1[(size_t)k * HID + n]);
      } else if (c < 384) {                // W2 [256][256] -> T2 [256][256]
        int idx = (c - 128) * 256 + t;
        int n = idx >> 8, k = idx & 255;
        T2[idx] = f2h(W2[(size_t)k * HID + n]);
      } else {                             // Wc [256][40] -> Tc [48][256] pad
        int idx = (c - 384) * 256 + t;
        int n = idx >> 8, k = idx & 255;
        float v = (n < NOUT) ? Wc[(size_t)k * NOUT + n] : 0.f;
        Tc[idx] = f2h(v);
      }
    }
  }
  grid.sync();

  // ---- phase 1: XCD-local degree histogram ----
  {
    int g = b & 7, chunk = b >> 3;
    int lo = g * NODES_PER_G, hi = lo + NODES_PER_G;
    int base = chunk * EDGE_CHUNK;
    for (int i = base + t; i < base + EDGE_CHUNK; i += 256) {
      int d = dstE[i];
      if (d >= lo && d < hi) atomicAdd(&count[d], 1);
    }
  }
  grid.sync();

  // ---- phase 2: per-chunk exclusive scan + dinv ----
  __shared__ int tmp[256];
  if (b < NBLK_SCAN) {
    int i = b * 256 + t;
    int v = (i < NNODES) ? count[i] : 0;
    if (i < NNODES) dinv[i] = rsqrtf((float)(v + 1));  // +1 self-loop
    tmp[t] = v;
    __syncthreads();
    for (int off = 1; off < 256; off <<= 1) {
      int x = (t >= off) ? tmp[t - off] : 0;
      __syncthreads();
      tmp[t] += x;
      __syncthreads();
    }
    if (i < NNODES) rowstart[i] = tmp[t] - v;  // exclusive within chunk
    if (t == 255) bsum[b] = tmp[255];
  }
  grid.sync();

  // ---- phase 3: scan of 196 block sums (block 0) ----
  if (b == 0) {
    int v = (t < NBLK_SCAN) ? bsum[t] : 0;
    tmp[t] = v;
    __syncthreads();
    for (int off = 1; off < 256; off <<= 1) {
      int x = (t >= off) ? tmp[t - off] : 0;
      __syncthreads();
      tmp[t] += x;
      __syncthreads();
    }
    if (t < NBLK_SCAN) boff[t] = tmp[t] - v;  // exclusive
  }
  grid.sync();

  // ---- phase 4: XCD-local scatter ----
  {
    int g = b & 7, chunk = b >> 3;
    int lo = g * NODES_PER_G, hi = lo + NODES_PER_G;
    int base = chunk * EDGE_CHUNK;
    for (int i = base + t; i < base + EDGE_CHUNK; i += 256) {
      int d = dstE[i];
      if (d >= lo && d < hi) {
        int p = rowstart[d] + boff[d >> 8] + atomicAdd(&cursor[d], 1);
        csr[p] = srcE[i];
      }
    }
  }
}

// ---------------- agg layer 1: half-wave fp16 gather (F=128) ----------------

__global__ __launch_bounds__(256) void k_agg1(const unsigned short* __restrict__ X,
                                              const int* __restrict__ rowstart,
                                              const int* __restrict__ boff,
                                              const int* __restrict__ csr,
                                              const float* __restrict__ dinv,
                                              uint2* __restrict__ Y) {
  int wave = threadIdx.x >> 6, lane = threadIdx.x & 63;
  int node = blockIdx.x * 4 + wave;
  if (node >= NNODES) return;
  int half = lane >> 5, l32 = lane & 31;
  float di = dinv[node];
  float a[4] = {0.f, 0.f, 0.f, 0.f};
  int e = rowstart[node] + boff[node >> 8];
  int end = (node + 1 < NNODES) ? rowstart[node + 1] + boff[(node + 1) >> 8] : NEDGES;
  for (; e + 8 <= end; e += 8) {
    int s0 = csr[e + 0 + half], s1 = csr[e + 2 + half];
    int s2 = csr[e + 4 + half], s3 = csr[e + 6 + half];
    float w0 = dinv[s0] * di, w1 = dinv[s1] * di;
    float w2 = dinv[s2] * di, w3 = dinv[s3] * di;
    u16x4 r0 = *reinterpret_cast<const u16x4*>(X + (size_t)s0 * F_IN + l32 * 4);
    u16x4 r1 = *reinterpret_cast<const u16x4*>(X + (size_t)s1 * F_IN + l32 * 4);
    u16x4 r2 = *reinterpret_cast<const u16x4*>(X + (size_t)s2 * F_IN + l32 * 4);
    u16x4 r3 = *reinterpret_cast<const u16x4*>(X + (size_t)s3 * F_IN + l32 * 4);
#pragma unroll
    for (int k = 0; k < 4; k++) {
      a[k] = fmaf(h2f(r0[k]), w0, a[k]);
      a[k] = fmaf(h2f(r1[k]), w1, a[k]);
      a[k] = fmaf(h2f(r2[k]), w2, a[k]);
      a[k] = fmaf(h2f(r3[k]), w3, a[k]);
    }
  }
  for (; e + 2 <= end; e += 2) {
    int s = csr[e + half];
    float w = dinv[s] * di;
    u16x4 r = *reinterpret_cast<const u16x4*>(X + (size_t)s * F_IN + l32 * 4);
#pragma unroll
    for (int k = 0; k < 4; k++) a[k] = fmaf(h2f(r[k]), w, a[k]);
  }
  if (e < end) {  // odd remainder: both halves read it, half 1 weight 0
    int s = csr[e];
    float w = half ? 0.f : dinv[s] * di;
    u16x4 r = *reinterpret_cast<const u16x4*>(X + (size_t)s * F_IN + l32 * 4);
#pragma unroll
    for (int k = 0; k < 4; k++) a[k] = fmaf(h2f(r[k]), w, a[k]);
  }
#pragma unroll
  for (int k = 0; k < 4; k++) a[k] += __shfl_xor(a[k], 32);
  if (half == 0) {
    u16x4 self = *reinterpret_cast<const u16x4*>(X + (size_t)node * F_IN + l32 * 4);
    float dd = di * di;
#pragma unroll
    for (int k = 0; k < 4; k++) a[k] = fmaf(h2f(self[k]), dd, a[k]);
    uint2 o;
    o.x = (unsigned)f2h(a[0]) | ((unsigned)f2h(a[1]) << 16);
    o.y = (unsigned)f2h(a[2]) | ((unsigned)f2h(a[3]) << 16);
    Y[(size_t)node * 32 + l32] = o;
  }
}

// ---------------- agg layer 2: half-wave fp16 gather (F=256) ----------------

__global__ __launch_bounds__(256) void k_agg2(const unsigned short* __restrict__ H,
                                              const int* __restrict__ rowstart,
                                              const int* __restrict__ boff,
                                              const int* __restrict__ csr,
                                              const float* __restrict__ dinv,
                                              uint4* __restrict__ Y) {
  int wave = threadIdx.x >> 6, lane = threadIdx.x & 63;
  int node = blockIdx.x * 4 + wave;
  if (node >= NNODES) return;
  int half = lane >> 5, l32 = lane & 31;
  float di = dinv[node];
  float a[8] = {0.f, 0.f, 0.f, 0.f, 0.f, 0.f, 0.f, 0.f};
  int e = rowstart[node] + boff[node >> 8];
  int end = (node + 1 < NNODES) ? rowstart[node + 1] + boff[(node + 1) >> 8] : NEDGES;
  for (; e + 8 <= end; e += 8) {
    int s0 = csr[e + 0 + half], s1 = csr[e + 2 + half];
    int s2 = csr[e + 4 + half], s3 = csr[e + 6 + half];
    float w0 = dinv[s0] * di, w1 = dinv[s1] * di;
    float w2 = dinv[s2] * di, w3 = dinv[s3] * di;
    u16x8 r0 = *reinterpret_cast<const u16x8*>(H + (size_t)s0 * HID + l32 * 8);
    u16x8 r1 = *reinterpret_cast<const u16x8*>(H + (size_t)s1 * HID + l32 * 8);
    u16x8 r2 = *reinterpret_cast<const u16x8*>(H + (size_t)s2 * HID + l32 * 8);
    u16x8 r3 = *reinterpret_cast<const u16x8*>(H + (size_t)s3 * HID + l32 * 8);
#pragma unroll
    for (int k = 0; k < 8; k++) {
      a[k] = fmaf(h2f(r0[k]), w0, a[k]);
      a[k] = fmaf(h2f(r1[k]), w1, a[k]);
      a[k] = fmaf(h2f(r2[k]), w2, a[k]);
      a[k] = fmaf(h2f(r3[k]), w3, a[k]);
    }
  }
  for (; e + 2 <= end; e += 2) {
    int s = csr[e + half];
    float w = dinv[s] * di;
    u16x8 r = *reinterpret_cast<const u16x8*>(H + (size_t)s * HID + l32 * 8);
#pragma unroll
    for (int k = 0; k < 8; k++) a[k] = fmaf(h2f(r[k]), w, a[k]);
  }
  if (e < end) {
    int s = csr[e];
    float w = half ? 0.f : dinv[s] * di;
    u16x8 r = *reinterpret_cast<const u16x8*>(H + (size_t)s * HID + l32 * 8);
#pragma unroll
    for (int k = 0; k < 8; k++) a[k] = fmaf(h2f(r[k]), w, a[k]);
  }
#pragma unroll
  for (int k = 0; k < 8; k++) a[k] += __shfl_xor(a[k], 32);
  if (half == 0) {
    u16x8 self = *reinterpret_cast<const u16x8*>(H + (size_t)node * HID + l32 * 8);
    float dd = di * di;
#pragma unroll
    for (int k = 0; k < 8; k++) a[k] = fmaf(h2f(self[k]), dd, a[k]);
    uint4 o;
    o.x = (unsigned)f2h(a[0]) | ((unsigned)f2h(a[1]) << 16);
    o.y = (unsigned)f2h(a[2]) | ((unsigned)f2h(a[3]) << 16);
    o.z = (unsigned)f2h(a[4]) | ((unsigned)f2h(a[5]) << 16);
    o.w = (unsigned)f2h(a[6]) | ((unsigned)f2h(a[7]) << 16);
    Y[(size_t)node * 32 + l32] = o;
  }
}

// ---------------- fp16 MFMA GEMM (layer 1), double-buffered ----------------
// C = A[MxK] @ B[KxN] + bias, ReLU, fp16 row-major out.

__global__ __launch_bounds__(256) void k_mgemm(const unsigned short* __restrict__ Ag,
                                               const unsigned short* __restrict__ Btg,
                                               const float* __restrict__ bias,
                                               unsigned short* __restrict__ Cout,
                                               int M, int Nc, int K) {
  __shared__ unsigned short Ah[2][128 * 40];
  __shared__ unsigned short Bh[2][128 * 40];
  int tid = threadIdx.x;
  int lane = tid & 63, w = tid >> 6;
  int wr = w >> 1, wc = w & 1;
  int bm = blockIdx.x * 128, bn = blockIdx.y * 128;
  int l15 = lane & 15, kg = lane >> 4;
  int row0 = tid >> 2, kq0 = (tid & 3) * 8;
  int gm0 = bm + row0, gm1 = bm + row0 + 64;

  f32x4 zero = {0.f, 0.f, 0.f, 0.f};
  f32x4 acc[4][4];
#pragma unroll
  for (int i = 0; i < 4; i++)
#pragma unroll
    for (int j = 0; j < 4; j++) acc[i][j] = zero;

  uint4 ra0, ra1, rb0, rb1;
  const uint4 z4 = {0, 0, 0, 0};
#define LOADT(KT)                                                                    \
  {                                                                                  \
    ra0 = z4; ra1 = z4;                                                              \
    if (gm0 < M) ra0 = *reinterpret_cast<const uint4*>(Ag + (size_t)gm0 * K + (KT) + kq0); \
    if (gm1 < M) ra1 = *reinterpret_cast<const uint4*>(Ag + (size_t)gm1 * K + (KT) + kq0); \
    rb0 = *reinterpret_cast<const uint4*>(Btg + (size_t)(bn + row0) * K + (KT) + kq0);     \
    rb1 = *reinterpret_cast<const uint4*>(Btg + (size_t)(bn + row0 + 64) * K + (KT) + kq0);\
  }
#define STORET(B)                                                       \
  {                                                                     \
    *reinterpret_cast<uint4*>(&Ah[B][row0 * 40 + kq0]) = ra0;           \
    *reinterpret_cast<uint4*>(&Ah[B][(row0 + 64) * 40 + kq0]) = ra1;    \
    *reinterpret_cast<uint4*>(&Bh[B][row0 * 40 + kq0]) = rb0;           \
    *reinterpret_cast<uint4*>(&Bh[B][(row0 + 64) * 40 + kq0]) = rb1;    \
  }

  LOADT(0);
  STORET(0);
  __syncthreads();
  int nt = K >> 5, cur = 0;
  for (int t = 0; t < nt; t++) {
    bool pf = (t + 1 < nt);
    if (pf) LOADT((t + 1) << 5);
    f16x8 fa[4], fb[4];
#pragma unroll
    for (int f = 0; f < 4; f++) {
      fa[f] = *reinterpret_cast<const f16x8*>(&Ah[cur][(wr * 64 + f * 16 + l15) * 40 + kg * 8]);
      fb[f] = *reinterpret_cast<const f16x8*>(&Bh[cur][(wc * 64 + f * 16 + l15) * 40 + kg * 8]);
    }
#pragma unroll
    for (int i = 0; i < 4; i++)
#pragma unroll
      for (int j = 0; j < 4; j++)
        acc[i][j] = __builtin_amdgcn_mfma_f32_16x16x32_f16(fa[i], fb[j], acc[i][j], 0, 0, 0);
    if (pf) STORET(cur ^ 1);
    __syncthreads();
    cur ^= 1;
  }
#undef LOADT
#undef STORET

  int r0 = kg * 4;
#pragma unroll
  for (int i = 0; i < 4; i++) {
    int gmBase = bm + wr * 64 + i * 16 + r0;
#pragma unroll
    for (int r = 0; r < 4; r++) {
      int gm = gmBase + r;
      if (gm >= M) continue;
#pragma unroll
      for (int j = 0; j < 4; j++) {
        int gn = bn + wc * 64 + j * 16 + l15;
        float v = acc[i][j][r] + bias[gn];
        v = fmaxf(v, 0.f);
        Cout[(size_t)gm * Nc + gn] = f2h(v);
      }
    }
  }
}

// ------- fused layer-2 GEMM + classifier: out = relu(aggh@W2+b2)@Wc + bc ----

__global__ __launch_bounds__(256) void k_g2cls(const unsigned short* __restrict__ Ag,
                                               const unsigned short* __restrict__ W2t,
                                               const float* __restrict__ b2,
                                               const unsigned short* __restrict__ Wct,
                                               const float* __restrict__ bc,
                                               float* __restrict__ out, int M) {
  __shared__ unsigned short Ah[128 * 40];   // 10.2 KB
  __shared__ unsigned short Bh[128 * 40];   // 10.2 KB
  __shared__ unsigned short H2[128 * 136];  // 34.8 KB
  __shared__ unsigned short WcS[48 * 40];   // 3.8 KB
  int tid = threadIdx.x;
  int lane = tid & 63, w = tid >> 6;
  int wr = w >> 1, wc = w & 1;
  int bm = blockIdx.x * 128;
  int l15 = lane & 15, kg = lane >> 4;
  int row0 = tid >> 2, kq0 = (tid & 3) * 8;
  int gm0 = bm + row0, gm1 = bm + row0 + 64;

  f32x4 zero = {0.f, 0.f, 0.f, 0.f};
  f32x4 clsacc[2][3];
#pragma unroll
  for (int f = 0; f < 2; f++)
#pragma unroll
    for (int j = 0; j < 3; j++) clsacc[f][j] = zero;

  for (int halfN = 0; halfN < 2; halfN++) {
    f32x4 acc[4][4];
#pragma unroll
    for (int i = 0; i < 4; i++)
#pragma unroll
      for (int j = 0; j < 4; j++) acc[i][j] = zero;
    int bn = halfN * 128;
    for (int kt = 0; kt < HID; kt += 32) {
      uint4 ra0 = {0, 0, 0, 0}, ra1 = {0, 0, 0, 0};
      if (gm0 < M) ra0 = *reinterpret_cast<const uint4*>(Ag + (size_t)gm0 * HID + kt + kq0);
      if (gm1 < M) ra1 = *reinterpret_cast<const uint4*>(Ag + (size_t)gm1 * HID + kt + kq0);
      uint4 rb0 = *reinterpret_cast<const uint4*>(W2t + (size_t)(bn + row0) * HID + kt + kq0);
      uint4 rb1 = *reinterpret_cast<const uint4*>(W2t + (size_t)(bn + row0 + 64) * HID + kt + kq0);
      *reinterpret_cast<uint4*>(&Ah[row0 * 40 + kq0]) = ra0;
      *reinterpret_cast<uint4*>(&Ah[(row0 + 64) * 40 + kq0]) = ra1;
      *reinterpret_cast<uint4*>(&Bh[row0 * 40 + kq0]) = rb0;
      *reinterpret_cast<uint4*>(&Bh[(row0 + 64) * 40 + kq0]) = rb1;
      __syncthreads();
      f16x8 fa[4], fb[4];
#pragma unroll
      for (int f = 0; f < 4; f++) {
        fa[f] = *reinterpret_cast<const f16x8*>(&Ah[(wr * 64 + f * 16 + l15) * 40 + kg * 8]);
        fb[f] = *reinterpret_cast<const f16x8*>(&Bh[(wc * 64 + f * 16 + l15) * 40 + kg * 8]);
      }
#pragma unroll
      for (int i = 0; i < 4; i++)
#pragma unroll
        for (int j = 0; j < 4; j++)
          acc[i][j] = __builtin_amdgcn_mfma_f32_16x16x32_f16(fa[i], fb[j], acc[i][j], 0, 0, 0);
      __syncthreads();
    }
    int r0 = kg * 4;
#pragma unroll
    for (int i = 0; i < 4; i++)
#pragma unroll
      for (int r = 0; r < 4; r++) {
        int lrow = wr * 64 + i * 16 + r0 + r;
#pragma unroll
        for (int j = 0; j < 4; j++) {
          int lcol = wc * 64 + j * 16 + l15;
          float v = acc[i][j][r] + b2[bn + lcol];
          H2[lrow * 136 + lcol] = f2h(fmaxf(v, 0.f));
        }
      }
    __syncthreads();
    for (int kt2 = 0; kt2 < 128; kt2 += 32) {
      if (tid < 192) {
        int row = tid >> 2, kq = (tid & 3) * 8;
        *reinterpret_cast<uint4*>(&WcS[row * 40 + kq]) =
            *reinterpret_cast<const uint4*>(Wct + (size_t)row * HID + halfN * 128 + kt2 + kq);
      }
      __syncthreads();
      f16x8 fa[2], fb[3];
#pragma unroll
      for (int f = 0; f < 2; f++)
        fa[f] = *reinterpret_cast<const f16x8*>(&H2[(w * 32 + f * 16 + l15) * 136 + kt2 + kg * 8]);
#pragma unroll
      for (int j = 0; j < 3; j++)
        fb[j] = *reinterpret_cast<const f16x8*>(&WcS[(j * 16 + l15) * 40 + kg * 8]);
#pragma unroll
      for (int f = 0; f < 2; f++)
#pragma unroll
        for (int j = 0; j < 3; j++)
          clsacc[f][j] = __builtin_amdgcn_mfma_f32_16x16x32_f16(fa[f], fb[j], clsacc[f][j], 0, 0, 0);
      __syncthreads();
    }
  }
  int r0 = kg * 4;
#pragma unroll
  for (int f = 0; f < 2; f++) {
    int gmBase = bm + w * 32 + f * 16 + r0;
#pragma unroll
    for (int r = 0; r < 4; r++) {
      int gm = gmBase + r;
      if (gm >= M) continue;
#pragma unroll
      for (int j = 0; j < 3; j++) {
        int gn = j * 16 + l15;
        if (gn >= NOUT) continue;
        out[(size_t)gm * NOUT + gn] = clsacc[f][j][r] + bc[gn];
      }
    }
  }
}

// ---------------- launch ----------------

extern "C" void kernel_launch(void* const* d_in, const int* in_sizes, int n_in,
                              void* d_out, int out_size, void* d_ws, size_t ws_size,
                              hipStream_t stream) {
  (void)in_sizes; (void)n_in; (void)out_size; (void)ws_size;
  const float* x  = (const float*)d_in[0];
  const float* W1 = (const float*)d_in[1];
  const float* b1 = (const float*)d_in[2];
  const float* W2 = (const float*)d_in[3];
  const float* b2 = (const float*)d_in[4];
  const float* Wc = (const float*)d_in[5];
  const float* bc = (const float*)d_in[6];
  const int* edge = (const int*)d_in[7];
  const int* srcE = edge;
  const int* dstE = edge + NEDGES;
  float* out = (float*)d_out;

  char* ws = (char*)d_ws;
  int*   rowstart = (int*)(ws + OFF_ROWSTART);
  float* dinv     = (float*)(ws + OFF_DINV);
  int*   csr      = (int*)(ws + OFF_CSR);
  int*   boff     = (int*)(ws + OFF_BOFF);
  unsigned short* W1t  = (unsigned short*)(ws + OFF_W1T);
  unsigned short* W2t  = (unsigned short*)(ws + OFF_W2T);
  unsigned short* Wct  = (unsigned short*)(ws + OFF_WCT);
  unsigned short* xh   = (unsigned short*)(ws + OFF_XH);
  unsigned short* aggx = (unsigned short*)(ws + OFF_AGGX);
  unsigned short* h1   = (unsigned short*)(ws + OFF_H1);
  unsigned short* aggh = (unsigned short*)(ws + OFF_AGGH);

  // cooperative CSR build (zero | cast | prep -> degree -> scan -> scatter)
  {
    void* args[] = {(void*)&x, (void*)&srcE, (void*)&dstE,
                    (void*)&W1, (void*)&W2, (void*)&Wc, (void*)&ws};
    hipLaunchCooperativeKernel((const void*)k_csr, dim3(CSR_BLOCKS), dim3(256),
                               args, 0, stream);
  }

  // layer 1
  k_agg1<<<(NNODES + 3) / 4, 256, 0, stream>>>(xh, rowstart, boff, csr, dinv, (uint2*)aggx);
  {
    dim3 grid((NNODES + 127) / 128, HID / 128);
    k_mgemm<<<grid, 256, 0, stream>>>(aggx, W1t, b1, h1, NNODES, HID, F_IN);
  }
  // layer 2 + classifier (fused)
  k_agg2<<<(NNODES + 3) / 4, 256, 0, stream>>>(h1, rowstart, boff, csr, dinv, (uint4*)aggh);
  k_g2cls<<<(NNODES + 127) / 128, 256, 0, stream>>>(aggh, W2t, b2, Wct, bc, out, NNODES);
}